// Round 13
// baseline (4739.938 us; speedup 1.0000x reference)
//
#include <hip/hip_runtime.h>
#include <stdint.h>

// Problem constants
#define N_ROWS 32768
#define KCODES 8192
#define DIM    512
#define DECAYF 0.8f
#define EPSF   1e-5f
#define CAP    96

// d_out layout (float32, reference return order)
#define OUT_QUANT 0
#define OUT_IND   (N_ROWS * DIM)
#define OUT_CSN   (OUT_IND + N_ROWS)
#define OUT_AVG   (OUT_CSN + KCODES)
#define OUT_NORM  (OUT_AVG + KCODES * DIM)

// During dist_k the quant region (64 MiB) holds Xh+Xm planes; rewritten by quant_slot_k.
// avg/csn regions initialized pre-dist (dist touches only quant region + ws).
// ws: [0,256K) best; [256K,288K) norm2; [288K] S; [+4] inv_cs; [1MiB) Eh, Em; [20MiB) cnt, rowlist.

typedef _Float16 f16x8 __attribute__((ext_vector_type(8)));
typedef __attribute__((ext_vector_type(4))) float f32x4;

__device__ __forceinline__ unsigned int enc_f(float v) {
    unsigned int b = __float_as_uint(v);
    return (b & 0x80000000u) ? ~b : (b | 0x80000000u);
}

__device__ __forceinline__ void gl16(const _Float16* g, const char* lds) {
    __builtin_amdgcn_global_load_lds(
        (const __attribute__((address_space(1))) unsigned int*)g,
        (__attribute__((address_space(3))) unsigned int*)lds, 16, 0, 0);
}

// ---- merged prep: blocks [0,8192) split X (+best/cnt/csn/avg init); [8192,10240) split E (+norm2) ----
__global__ void prep_k(const float* __restrict__ x, const float* __restrict__ embed,
                       _Float16* __restrict__ Xh, _Float16* __restrict__ Xm,
                       _Float16* __restrict__ Eh, _Float16* __restrict__ Em,
                       unsigned long long* __restrict__ best, unsigned int* __restrict__ cnt,
                       const float* __restrict__ cs, const float* __restrict__ eavg,
                       float* __restrict__ out, float* __restrict__ norm2) {
    if (blockIdx.x < 8192) {
        int i = blockIdx.x * 256 + threadIdx.x;        // < 2097152
        if (i < N_ROWS) best[i] = 0ull;
        if (i < KCODES) { cnt[i] = 0u; out[OUT_CSN + i] = DECAYF * cs[i]; }
        if (i < KCODES * DIM / 4) {
            float4 v = ((const float4*)eavg)[i];
            v.x *= DECAYF; v.y *= DECAYF; v.z *= DECAYF; v.w *= DECAYF;
            ((float4*)(out + OUT_AVG))[i] = v;
        }
        const float4* s4 = (const float4*)x;
        float4 v0 = s4[(size_t)i * 2], v1 = s4[(size_t)i * 2 + 1];
        float f[8] = {v0.x, v0.y, v0.z, v0.w, v1.x, v1.y, v1.z, v1.w};
        f16x8 hv, mv;
        #pragma unroll
        for (int j = 0; j < 8; ++j) {
            _Float16 h = (_Float16)f[j];
            float r = f[j] - (float)h;
            hv[j] = h;
            mv[j] = (_Float16)(r * 1024.0f);
        }
        *(f16x8*)(Xh + (size_t)i * 8) = hv;
        *(f16x8*)(Xm + (size_t)i * 8) = mv;
    } else {
        int i = (blockIdx.x - 8192) * 256 + threadIdx.x;   // < 524288
        const float4* s4 = (const float4*)embed;
        float4 v0 = s4[(size_t)i * 2], v1 = s4[(size_t)i * 2 + 1];
        float f[8] = {v0.x, v0.y, v0.z, v0.w, v1.x, v1.y, v1.z, v1.w};
        f16x8 hv, mv;
        float s = 0.f;
        #pragma unroll
        for (int j = 0; j < 8; ++j) {
            _Float16 h = (_Float16)f[j];
            float r = f[j] - (float)h;
            hv[j] = h;
            mv[j] = (_Float16)(r * 1024.0f);
            s += f[j] * f[j];
        }
        *(f16x8*)(Eh + (size_t)i * 8) = hv;
        *(f16x8*)(Em + (size_t)i * 8) = mv;
        #pragma unroll
        for (int off = 32; off; off >>= 1) s += __shfl_down(s, off);
        if ((threadIdx.x & 63) == 0) norm2[i >> 6] = s;
    }
}

// ---- K1: f16 3-pass dual-acc MFMA GEMM; Ah/Am/Bh in LDS dbuf, Em in asm-reg dbuf ----
#define BM 128
#define BN 128
#define BK 32
#define TILEB 8192      // bytes per plane tile: 128 rows x 32 f16
#define LBUF  24576     // one LDS buffer: 3 planes (Ah Am Bh)

__global__ __launch_bounds__(256, 3) void dist_k(
    const _Float16* __restrict__ Xh, const _Float16* __restrict__ Xm,
    const _Float16* __restrict__ Eh, const _Float16* __restrict__ Em,
    const float* __restrict__ norm2, unsigned long long* __restrict__ best)
{
    __shared__ _Float16 smem[2 * 3 * 4096];   // 48 KiB: 2 x (Ah Am Bh)
    char* sb = (char*)smem;

    const int tid = threadIdx.x;
    const int w = tid >> 6, l = tid & 63;

    // XCD column-band mapping (R6-proven)
    int b = blockIdx.x;
    int xcd = b & 7;
    int local = b >> 3;
    int bxl = local & 7;
    int by = local >> 3;
    int bx = xcd * 8 + bxl;
    const int rBase = by * BM, cBase = bx * BN;

    // staging geometry (R6-proven): linear LDS dest, pre-swizzled source
    int o0 = (w << 10) | (l << 4);
    int o1 = o0 + 4096;
    int row0 = o0 >> 6, kb0 = (o0 >> 4) & 3;
    int row1 = o1 >> 6, kb1 = (o1 >> 4) & 3;
    int c0 = (kb0 ^ ((row0 >> 1) & 3)) << 3;
    int c1 = (kb1 ^ ((row1 >> 1) & 3)) << 3;
    unsigned offA0 = (unsigned)(rBase + row0) * DIM + c0;
    unsigned offA1 = (unsigned)(rBase + row1) * DIM + c1;
    unsigned offB0 = (unsigned)(cBase + row0) * DIM + c0;
    unsigned offB1 = (unsigned)(cBase + row1) * DIM + c1;
    const int w1024 = w << 10;

    const int wr = w >> 1, wc = w & 1;
    const int ln = l & 15, kq = l >> 4;

    const int rA = wr * 64 + ln;
    const int baA = rA * 64 + ((kq ^ ((rA >> 1) & 3)) << 4);
    const int rB = wc * 64 + ln;
    const int baB = rB * 64 + ((kq ^ ((rB >> 1) & 3)) << 4);

    // Em direct-global base (line-efficient: 16 rows x 64 B fully consumed)
    const _Float16* gBm = Em + (size_t)(cBase + wc * 64 + ln) * DIM + kq * 8;

    f32x4 acc1[4][4], acc2[4][4];
    #pragma unroll
    for (int i = 0; i < 4; ++i)
        #pragma unroll
        for (int j = 0; j < 4; ++j) {
            acc1[i][j] = (f32x4){0.f, 0.f, 0.f, 0.f};
            acc2[i][j] = (f32x4){0.f, 0.f, 0.f, 0.f};
        }

    float4 bmA[4], bmB[4];   // asm-loaded Em double buffer (compiler-invisible loads)

    #define STAGE6(BUFOFF, D0) { \
        gl16(Xh + offA0 + (D0), sb + (BUFOFF) + 0 * TILEB + w1024); \
        gl16(Xh + offA1 + (D0), sb + (BUFOFF) + 0 * TILEB + 4096 + w1024); \
        gl16(Xm + offA0 + (D0), sb + (BUFOFF) + 1 * TILEB + w1024); \
        gl16(Xm + offA1 + (D0), sb + (BUFOFF) + 1 * TILEB + 4096 + w1024); \
        gl16(Eh + offB0 + (D0), sb + (BUFOFF) + 2 * TILEB + w1024); \
        gl16(Eh + offB1 + (D0), sb + (BUFOFF) + 2 * TILEB + 4096 + w1024); \
    }

    #define ASMB(BMv, D0) { \
        asm volatile("global_load_dwordx4 %0, %1, off" : "=v"(BMv[0]) : "v"(gBm + 0 * 8192 + (D0))); \
        asm volatile("global_load_dwordx4 %0, %1, off" : "=v"(BMv[1]) : "v"(gBm + 1 * 8192 + (D0))); \
        asm volatile("global_load_dwordx4 %0, %1, off" : "=v"(BMv[2]) : "v"(gBm + 2 * 8192 + (D0))); \
        asm volatile("global_load_dwordx4 %0, %1, off" : "=v"(BMv[3]) : "v"(gBm + 3 * 8192 + (D0))); \
    }

    // prologue: chunk 0 -> buf0 + bmA; drain stage (6 oldest), leave Em(0) in flight
    STAGE6(0, 0)
    ASMB(bmA, 0)
    asm volatile("s_waitcnt vmcnt(8)" ::: "memory");
    __builtin_amdgcn_s_barrier();
    __builtin_amdgcn_sched_barrier(0);

    #pragma unroll
    for (int t = 0; t < 16; ++t) {
        const int X = (t & 1) ? LBUF : 0;
        const int Y = X ^ LBUF;
        const int dn = t * 32 + 32;
        // issue next chunk: 6 stage loads then 8 Em reg loads (order matters for vmcnt math)
        if (t < 15) { STAGE6(Y, dn) }
        if (t < 15) {
            if (t & 1) { ASMB(bmA, dn) } else { ASMB(bmB, dn) }
        }
        // pass 1: ah x bh from LDS buf X
        f16x8 ah[4], am[4], bh[4];
        #pragma unroll
        for (int ai = 0; ai < 4; ++ai)
            ah[ai] = *(const f16x8*)(sb + X + 0 * TILEB + baA + ai * 1024);
        #pragma unroll
        for (int bj = 0; bj < 4; ++bj)
            bh[bj] = *(const f16x8*)(sb + X + 2 * TILEB + baB + bj * 1024);
        #pragma unroll
        for (int bj = 0; bj < 4; ++bj)
            #pragma unroll
            for (int ai = 0; ai < 4; ++ai)
                acc1[ai][bj] = __builtin_amdgcn_mfma_f32_16x16x32_f16(ah[ai], bh[bj], acc1[ai][bj], 0, 0, 0);
        // wait for this chunk's Em set (loaded last iter; 14 younger ops stay in flight)
        if (t < 15) {
            asm volatile("s_waitcnt vmcnt(14)" ::: "memory");
        } else {
            asm volatile("s_waitcnt vmcnt(0)" ::: "memory");
        }
        __builtin_amdgcn_sched_barrier(0);
        // pass 2: ah x bm (acc2)
        #pragma unroll
        for (int bj = 0; bj < 4; ++bj) {
            f16x8 bm = __builtin_bit_cast(f16x8, (t & 1) ? bmB[bj] : bmA[bj]);
            #pragma unroll
            for (int ai = 0; ai < 4; ++ai)
                acc2[ai][bj] = __builtin_amdgcn_mfma_f32_16x16x32_f16(ah[ai], bm, acc2[ai][bj], 0, 0, 0);
        }
        // pass 3: am x bh (acc2)
        #pragma unroll
        for (int ai = 0; ai < 4; ++ai)
            am[ai] = *(const f16x8*)(sb + X + 1 * TILEB + baA + ai * 1024);
        #pragma unroll
        for (int bj = 0; bj < 4; ++bj)
            #pragma unroll
            for (int ai = 0; ai < 4; ++ai)
                acc2[ai][bj] = __builtin_amdgcn_mfma_f32_16x16x32_f16(am[ai], bh[bj], acc2[ai][bj], 0, 0, 0);
        // end of chunk: drain next chunk's stage (leave its 8 Em loads in flight), barrier
        if (t < 15) {
            asm volatile("s_waitcnt vmcnt(8)" ::: "memory");
            __builtin_amdgcn_s_barrier();
            __builtin_amdgcn_sched_barrier(0);
        }
    }
    #undef STAGE6
    #undef ASMB

    // ---- epilogue: dot = acc1 + 2^-10*acc2 ; dist = 2*dot - ||e||^2 ; argmax ----
    const float S = 0.0009765625f;
    float n2v[4];
    #pragma unroll
    for (int bj = 0; bj < 4; ++bj)
        n2v[bj] = norm2[cBase + wc * 64 + bj * 16 + ln];

    #pragma unroll
    for (int ai = 0; ai < 4; ++ai) {
        #pragma unroll
        for (int r = 0; r < 4; ++r) {
            float bval = -3.4e38f;
            int bidx = 0;
            #pragma unroll
            for (int bj = 0; bj < 4; ++bj) {
                float v = 2.f * (acc1[ai][bj][r] + S * acc2[ai][bj][r]) - n2v[bj];
                if (v > bval) { bval = v; bidx = cBase + wc * 64 + bj * 16 + ln; }
            }
            #pragma unroll
            for (int off = 1; off < 16; off <<= 1) {
                float ov = __shfl_xor(bval, off);
                int   oi = __shfl_xor(bidx, off);
                if (ov > bval || (ov == bval && oi < bidx)) { bval = ov; bidx = oi; }
            }
            if (ln == 0) {
                unsigned long long key =
                    ((unsigned long long)enc_f(bval) << 32) | (unsigned int)(~(unsigned int)bidx);
                atomicMax(&best[rBase + wr * 64 + ai * 16 + kq * 4 + r], key);
            }
        }
    }
}

// ---- phase A: gather quantize + slot allocation (4 rows per 256-thread block) ----
__global__ void quant_slot_k(const float* __restrict__ x, const float* __restrict__ embed,
                             const unsigned long long* __restrict__ best,
                             unsigned int* __restrict__ cnt, unsigned int* __restrict__ rowlist,
                             float* __restrict__ out) {
    int row = blockIdx.x * 4 + (threadIdx.x >> 6);
    int lane = threadIdx.x & 63;
    int idx = (int)(~(unsigned int)best[row]);
    const float4* e = (const float4*)(embed + (size_t)idx * DIM);
    float4* q = (float4*)(out + OUT_QUANT + (size_t)row * DIM);
    q[lane] = e[lane];
    q[lane + 64] = e[lane + 64];
    int pos = 0;
    if (lane == 0) {
        out[OUT_IND + row] = (float)idx;
        pos = (int)atomicAdd(&cnt[idx], 1u);
        if (pos < CAP) rowlist[idx * CAP + pos] = (unsigned)row;
    }
    pos = __shfl(pos, 0);
    if (pos >= CAP) {   // overflow fallback (never for this data; correctness guard)
        const float4* xr = (const float4*)(x + (size_t)row * DIM);
        float* avg = out + OUT_AVG + (size_t)idx * DIM;
        #pragma unroll
        for (int j = lane; j < DIM / 4; j += 64) {
            float4 xv = xr[j];
            atomicAdd(&avg[j * 4 + 0], 0.2f * xv.x);
            atomicAdd(&avg[j * 4 + 1], 0.2f * xv.y);
            atomicAdd(&avg[j * 4 + 2], 0.2f * xv.z);
            atomicAdd(&avg[j * 4 + 3], 0.2f * xv.w);
        }
    }
}

// ---- phase B: per-code row-list reduce, atomic-free ----
__global__ void csum_k(const float* __restrict__ x, const unsigned int* __restrict__ cnt,
                       const unsigned int* __restrict__ rowlist, float* __restrict__ out) {
    int code = blockIdx.x, lane = threadIdx.x;
    int n = (int)cnt[code];
    if (n == 0) return;
    int m = n < CAP ? n : CAP;
    float4 a0 = {0.f, 0.f, 0.f, 0.f}, a1 = {0.f, 0.f, 0.f, 0.f};
    for (int t = 0; t < m; ++t) {
        int row = (int)rowlist[code * CAP + t];
        const float4* xr = (const float4*)(x + (size_t)row * DIM);
        float4 v0 = xr[lane], v1 = xr[lane + 64];
        a0.x += v0.x; a0.y += v0.y; a0.z += v0.z; a0.w += v0.w;
        a1.x += v1.x; a1.y += v1.y; a1.z += v1.z; a1.w += v1.w;
    }
    float4* av = (float4*)(out + OUT_AVG + (size_t)code * DIM);
    float4 c0 = av[lane], c1 = av[lane + 64];
    c0.x += 0.2f * a0.x; c0.y += 0.2f * a0.y; c0.z += 0.2f * a0.z; c0.w += 0.2f * a0.w;
    c1.x += 0.2f * a1.x; c1.y += 0.2f * a1.y; c1.z += 0.2f * a1.z; c1.w += 0.2f * a1.w;
    av[lane] = c0;
    av[lane + 64] = c1;
    if (lane == 0) out[OUT_CSN + code] += 0.2f * (float)n;
}

__global__ void sumInv_k(const float* __restrict__ out, float* __restrict__ Sout,
                         float* __restrict__ inv_cs) {
    __shared__ float red[4];
    float s = 0.f;
    for (int i = threadIdx.x; i < KCODES; i += 256) s += out[OUT_CSN + i];
    #pragma unroll
    for (int off = 32; off; off >>= 1) s += __shfl_down(s, off);
    if ((threadIdx.x & 63) == 0) red[threadIdx.x >> 6] = s;
    __syncthreads();
    float Sv = red[0] + red[1] + red[2] + red[3];
    if (threadIdx.x == 0) Sout[0] = Sv;
    for (int k = threadIdx.x; k < KCODES; k += 256)
        inv_cs[k] = (Sv + (float)KCODES * EPSF) / ((out[OUT_CSN + k] + EPSF) * Sv);
}

__global__ void normout_k(float* __restrict__ out, const float* __restrict__ inv_cs) {
    int i = blockIdx.x * 256 + threadIdx.x;
    const float4* avg = (const float4*)(out + OUT_AVG);
    float4* nrm = (float4*)(out + OUT_NORM);
    float inv = inv_cs[i >> 7];
    float4 v = avg[i];
    v.x *= inv; v.y *= inv; v.z *= inv; v.w *= inv;
    nrm[i] = v;
}

extern "C" void kernel_launch(void* const* d_in, const int* in_sizes, int n_in,
                              void* d_out, int out_size, void* d_ws, size_t ws_size,
                              hipStream_t stream) {
    const float* x     = (const float*)d_in[0];
    const float* embed = (const float*)d_in[1];
    const float* cs    = (const float*)d_in[2];
    const float* eavg  = (const float*)d_in[3];
    float* out = (float*)d_out;
    char*  w   = (char*)d_ws;

    unsigned long long* best = (unsigned long long*)w;
    float* norm2  = (float*)(w + 262144);
    float* Ssum   = (float*)(w + 294912);
    float* inv_cs = Ssum + 1;
    _Float16* Eh = (_Float16*)(w + (1u << 20));
    _Float16* Em = Eh + (size_t)KCODES * DIM;
    unsigned int* cnt     = (unsigned int*)(w + (20u << 20));
    unsigned int* rowlist = cnt + KCODES;

    _Float16* Xh = (_Float16*)out;
    _Float16* Xm = Xh + (size_t)N_ROWS * DIM;

    prep_k<<<10240, 256, 0, stream>>>(x, embed, Xh, Xm, Eh, Em, best, cnt, cs, eavg, out, norm2);
    dist_k<<<(N_ROWS / BM) * (KCODES / BN), 256, 0, stream>>>(Xh, Xm, Eh, Em, norm2, best);
    quant_slot_k<<<N_ROWS / 4, 256, 0, stream>>>(x, embed, best, cnt, rowlist, out);
    csum_k<<<KCODES, 64, 0, stream>>>(x, cnt, rowlist, out);
    sumInv_k<<<1, 256, 0, stream>>>(out, Ssum, inv_cs);
    normout_k<<<(KCODES * DIM / 4) / 256, 256, 0, stream>>>(out, inv_cs);
}

// Round 14
// 922.038 us; speedup vs baseline: 5.1407x; 5.1407x over previous
//
#include <hip/hip_runtime.h>
#include <stdint.h>

// Problem constants
#define N_ROWS 32768
#define KCODES 8192
#define DIM    512
#define DECAYF 0.8f
#define EPSF   1e-5f
#define CAP    96

// d_out layout (float32, reference return order)
#define OUT_QUANT 0
#define OUT_IND   (N_ROWS * DIM)
#define OUT_CSN   (OUT_IND + N_ROWS)
#define OUT_AVG   (OUT_CSN + KCODES)
#define OUT_NORM  (OUT_AVG + KCODES * DIM)

// During dist_k the quant region (64 MiB) holds Xh+Xm planes; rewritten by quant_slot_k.
// avg/csn regions initialized pre-dist (dist touches only quant region + ws).
// ws: [0,256K) best; [256K,288K) norm2; [288K] S; [+4] inv_cs; [1MiB) Eh, Em; [20MiB) cnt, rowlist.

typedef _Float16 f16x8 __attribute__((ext_vector_type(8)));
typedef __attribute__((ext_vector_type(4))) float f32x4;

__device__ __forceinline__ unsigned int enc_f(float v) {
    unsigned int b = __float_as_uint(v);
    return (b & 0x80000000u) ? ~b : (b | 0x80000000u);
}

__device__ __forceinline__ void gl16(const _Float16* g, const char* lds) {
    __builtin_amdgcn_global_load_lds(
        (const __attribute__((address_space(1))) unsigned int*)g,
        (__attribute__((address_space(3))) unsigned int*)lds, 16, 0, 0);
}

// ---- merged prep: blocks [0,8192) split X (+best/cnt/csn/avg init); [8192,10240) split E (+norm2) ----
__global__ void prep_k(const float* __restrict__ x, const float* __restrict__ embed,
                       _Float16* __restrict__ Xh, _Float16* __restrict__ Xm,
                       _Float16* __restrict__ Eh, _Float16* __restrict__ Em,
                       unsigned long long* __restrict__ best, unsigned int* __restrict__ cnt,
                       const float* __restrict__ cs, const float* __restrict__ eavg,
                       float* __restrict__ out, float* __restrict__ norm2) {
    if (blockIdx.x < 8192) {
        int i = blockIdx.x * 256 + threadIdx.x;        // < 2097152
        if (i < N_ROWS) best[i] = 0ull;
        if (i < KCODES) { cnt[i] = 0u; out[OUT_CSN + i] = DECAYF * cs[i]; }
        if (i < KCODES * DIM / 4) {
            float4 v = ((const float4*)eavg)[i];
            v.x *= DECAYF; v.y *= DECAYF; v.z *= DECAYF; v.w *= DECAYF;
            ((float4*)(out + OUT_AVG))[i] = v;
        }
        const float4* s4 = (const float4*)x;
        float4 v0 = s4[(size_t)i * 2], v1 = s4[(size_t)i * 2 + 1];
        float f[8] = {v0.x, v0.y, v0.z, v0.w, v1.x, v1.y, v1.z, v1.w};
        f16x8 hv, mv;
        #pragma unroll
        for (int j = 0; j < 8; ++j) {
            _Float16 h = (_Float16)f[j];
            float r = f[j] - (float)h;
            hv[j] = h;
            mv[j] = (_Float16)(r * 1024.0f);
        }
        *(f16x8*)(Xh + (size_t)i * 8) = hv;
        *(f16x8*)(Xm + (size_t)i * 8) = mv;
    } else {
        int i = (blockIdx.x - 8192) * 256 + threadIdx.x;   // < 524288
        const float4* s4 = (const float4*)embed;
        float4 v0 = s4[(size_t)i * 2], v1 = s4[(size_t)i * 2 + 1];
        float f[8] = {v0.x, v0.y, v0.z, v0.w, v1.x, v1.y, v1.z, v1.w};
        f16x8 hv, mv;
        float s = 0.f;
        #pragma unroll
        for (int j = 0; j < 8; ++j) {
            _Float16 h = (_Float16)f[j];
            float r = f[j] - (float)h;
            hv[j] = h;
            mv[j] = (_Float16)(r * 1024.0f);
            s += f[j] * f[j];
        }
        *(f16x8*)(Eh + (size_t)i * 8) = hv;
        *(f16x8*)(Em + (size_t)i * 8) = mv;
        #pragma unroll
        for (int off = 32; off; off >>= 1) s += __shfl_down(s, off);
        if ((threadIdx.x & 63) == 0) norm2[i >> 6] = s;
    }
}

// ---- K1: f16 3-pass dual-acc MFMA GEMM, counted-vmcnt 2-buffer pipeline (R6/R12, 846us) ----
#define BM 128
#define BN 128
#define BK 32
#define TILEB 8192      // bytes per plane tile: 128 rows x 32 f16
#define LBUF  32768     // one LDS buffer: 4 planes (Ah Am Bh Bm)

__global__ __launch_bounds__(256, 2) void dist_k(
    const _Float16* __restrict__ Xh, const _Float16* __restrict__ Xm,
    const _Float16* __restrict__ Eh, const _Float16* __restrict__ Em,
    const float* __restrict__ norm2, unsigned long long* __restrict__ best)
{
    __shared__ _Float16 smem[2 * 4 * 4096];   // 64 KiB: 2 x (Ah Am Bh Bm)
    char* sb = (char*)smem;

    const int tid = threadIdx.x;
    const int w = tid >> 6, l = tid & 63;

    // XCD column-band mapping: XCD (b&7) owns 8 consecutive bx; bx-minor, by-major.
    int b = blockIdx.x;
    int xcd = b & 7;
    int local = b >> 3;
    int bxl = local & 7;
    int by = local >> 3;
    int bx = xcd * 8 + bxl;
    const int rBase = by * BM, cBase = bx * BN;

    // staging: 2 rounds/plane, linear LDS dest, pre-swizzled source (granule ^ (row>>1)&3)
    int o0 = (w << 10) | (l << 4);
    int o1 = o0 + 4096;
    int row0 = o0 >> 6, kb0 = (o0 >> 4) & 3;
    int row1 = o1 >> 6, kb1 = (o1 >> 4) & 3;
    int c0 = (kb0 ^ ((row0 >> 1) & 3)) << 3;
    int c1 = (kb1 ^ ((row1 >> 1) & 3)) << 3;
    unsigned offA0 = (unsigned)(rBase + row0) * DIM + c0;
    unsigned offA1 = (unsigned)(rBase + row1) * DIM + c1;
    unsigned offB0 = (unsigned)(cBase + row0) * DIM + c0;
    unsigned offB1 = (unsigned)(cBase + row1) * DIM + c1;
    const int w1024 = w << 10;

    const int wr = w >> 1, wc = w & 1;     // 2x2 wave grid, 64x64 output each
    const int ln = l & 15, kq = l >> 4;

    // ds_read bases (proven conflict-free 16x16 geometry from R3)
    const int rA = wr * 64 + ln;
    const int baA = rA * 64 + ((kq ^ ((rA >> 1) & 3)) << 4);
    const int rB = wc * 64 + ln;
    const int baB = rB * 64 + ((kq ^ ((rB >> 1) & 3)) << 4);

    f32x4 acc1[4][4], acc2[4][4];
    #pragma unroll
    for (int i = 0; i < 4; ++i)
        #pragma unroll
        for (int j = 0; j < 4; ++j) {
            acc1[i][j] = (f32x4){0.f, 0.f, 0.f, 0.f};
            acc2[i][j] = (f32x4){0.f, 0.f, 0.f, 0.f};
        }

    #define STAGE(BUFOFF, D0) { \
        gl16(Xh + offA0 + (D0), sb + (BUFOFF) + 0 * TILEB + w1024); \
        gl16(Xh + offA1 + (D0), sb + (BUFOFF) + 0 * TILEB + 4096 + w1024); \
        gl16(Xm + offA0 + (D0), sb + (BUFOFF) + 1 * TILEB + w1024); \
        gl16(Xm + offA1 + (D0), sb + (BUFOFF) + 1 * TILEB + 4096 + w1024); \
        gl16(Eh + offB0 + (D0), sb + (BUFOFF) + 2 * TILEB + w1024); \
        gl16(Eh + offB1 + (D0), sb + (BUFOFF) + 2 * TILEB + 4096 + w1024); \
        gl16(Em + offB0 + (D0), sb + (BUFOFF) + 3 * TILEB + w1024); \
        gl16(Em + offB1 + (D0), sb + (BUFOFF) + 3 * TILEB + 4096 + w1024); \
    }

    #define COMPUTE(BUFOFF) { \
        f16x8 ah[4], am[4], bh[4], bm[4]; \
        _Pragma("unroll") \
        for (int ai = 0; ai < 4; ++ai) { \
            ah[ai] = *(const f16x8*)(sb + (BUFOFF) + 0 * TILEB + baA + ai * 1024); \
            am[ai] = *(const f16x8*)(sb + (BUFOFF) + 1 * TILEB + baA + ai * 1024); \
        } \
        _Pragma("unroll") \
        for (int bj = 0; bj < 4; ++bj) { \
            bh[bj] = *(const f16x8*)(sb + (BUFOFF) + 2 * TILEB + baB + bj * 1024); \
            bm[bj] = *(const f16x8*)(sb + (BUFOFF) + 3 * TILEB + baB + bj * 1024); \
        } \
        _Pragma("unroll") \
        for (int bj = 0; bj < 4; ++bj) \
            _Pragma("unroll") \
            for (int ai = 0; ai < 4; ++ai) \
                acc1[ai][bj] = __builtin_amdgcn_mfma_f32_16x16x32_f16(ah[ai], bh[bj], acc1[ai][bj], 0, 0, 0); \
        _Pragma("unroll") \
        for (int bj = 0; bj < 4; ++bj) \
            _Pragma("unroll") \
            for (int ai = 0; ai < 4; ++ai) \
                acc2[ai][bj] = __builtin_amdgcn_mfma_f32_16x16x32_f16(ah[ai], bm[bj], acc2[ai][bj], 0, 0, 0); \
        _Pragma("unroll") \
        for (int bj = 0; bj < 4; ++bj) \
            _Pragma("unroll") \
            for (int ai = 0; ai < 4; ++ai) \
                acc2[ai][bj] = __builtin_amdgcn_mfma_f32_16x16x32_f16(am[ai], bh[bj], acc2[ai][bj], 0, 0, 0); \
    }

    // T4 counted-vmcnt pipeline: never drain in-flight prefetch (R6-proven).
    STAGE(0, 0)
    #pragma unroll
    for (int it = 0; it < 8; ++it) {
        int d0 = it * 64;
        STAGE(LBUF, d0 + 32)
        asm volatile("s_waitcnt vmcnt(8)" ::: "memory");
        __builtin_amdgcn_s_barrier();
        __builtin_amdgcn_sched_barrier(0);
        COMPUTE(0)
        __builtin_amdgcn_s_barrier();
        if (it < 7) {
            STAGE(0, d0 + 64)
            asm volatile("s_waitcnt vmcnt(8)" ::: "memory");
        } else {
            asm volatile("s_waitcnt vmcnt(0)" ::: "memory");
        }
        __builtin_amdgcn_s_barrier();
        __builtin_amdgcn_sched_barrier(0);
        COMPUTE(LBUF)
        __builtin_amdgcn_s_barrier();
    }
    #undef STAGE
    #undef COMPUTE

    // ---- epilogue: dot = acc1 + 2^-10 * acc2 ; dist = 2*dot - ||e||^2 ; argmax ----
    const float S = 0.0009765625f;   // 2^-10
    float n2v[4];
    #pragma unroll
    for (int bj = 0; bj < 4; ++bj)
        n2v[bj] = norm2[cBase + wc * 64 + bj * 16 + ln];

    #pragma unroll
    for (int ai = 0; ai < 4; ++ai) {
        #pragma unroll
        for (int r = 0; r < 4; ++r) {
            float bval = -3.4e38f;
            int bidx = 0;
            #pragma unroll
            for (int bj = 0; bj < 4; ++bj) {
                float v = 2.f * (acc1[ai][bj][r] + S * acc2[ai][bj][r]) - n2v[bj];
                if (v > bval) { bval = v; bidx = cBase + wc * 64 + bj * 16 + ln; }
            }
            #pragma unroll
            for (int off = 1; off < 16; off <<= 1) {
                float ov = __shfl_xor(bval, off);
                int   oi = __shfl_xor(bidx, off);
                if (ov > bval || (ov == bval && oi < bidx)) { bval = ov; bidx = oi; }
            }
            if (ln == 0) {
                unsigned long long key =
                    ((unsigned long long)enc_f(bval) << 32) | (unsigned int)(~(unsigned int)bidx);
                atomicMax(&best[rBase + wr * 64 + ai * 16 + kq * 4 + r], key);
            }
        }
    }
}

// ---- phase A: gather quantize + slot allocation (4 rows per 256-thread block) ----
__global__ void quant_slot_k(const float* __restrict__ x, const float* __restrict__ embed,
                             const unsigned long long* __restrict__ best,
                             unsigned int* __restrict__ cnt, unsigned int* __restrict__ rowlist,
                             float* __restrict__ out) {
    int row = blockIdx.x * 4 + (threadIdx.x >> 6);
    int lane = threadIdx.x & 63;
    int idx = (int)(~(unsigned int)best[row]);
    const float4* e = (const float4*)(embed + (size_t)idx * DIM);
    float4* q = (float4*)(out + OUT_QUANT + (size_t)row * DIM);
    q[lane] = e[lane];
    q[lane + 64] = e[lane + 64];
    int pos = 0;
    if (lane == 0) {
        out[OUT_IND + row] = (float)idx;
        pos = (int)atomicAdd(&cnt[idx], 1u);
        if (pos < CAP) rowlist[idx * CAP + pos] = (unsigned)row;
    }
    pos = __shfl(pos, 0);
    if (pos >= CAP) {   // overflow fallback (correctness guard)
        const float4* xr = (const float4*)(x + (size_t)row * DIM);
        float* avg = out + OUT_AVG + (size_t)idx * DIM;
        #pragma unroll
        for (int j = lane; j < DIM / 4; j += 64) {
            float4 xv = xr[j];
            atomicAdd(&avg[j * 4 + 0], 0.2f * xv.x);
            atomicAdd(&avg[j * 4 + 1], 0.2f * xv.y);
            atomicAdd(&avg[j * 4 + 2], 0.2f * xv.z);
            atomicAdd(&avg[j * 4 + 3], 0.2f * xv.w);
        }
    }
}

// ---- phase B: per-code row-list reduce, atomic-free ----
__global__ void csum_k(const float* __restrict__ x, const unsigned int* __restrict__ cnt,
                       const unsigned int* __restrict__ rowlist, float* __restrict__ out) {
    int code = blockIdx.x, lane = threadIdx.x;
    int n = (int)cnt[code];
    if (n == 0) return;
    int m = n < CAP ? n : CAP;
    float4 a0 = {0.f, 0.f, 0.f, 0.f}, a1 = {0.f, 0.f, 0.f, 0.f};
    for (int t = 0; t < m; ++t) {
        int row = (int)rowlist[code * CAP + t];
        const float4* xr = (const float4*)(x + (size_t)row * DIM);
        float4 v0 = xr[lane], v1 = xr[lane + 64];
        a0.x += v0.x; a0.y += v0.y; a0.z += v0.z; a0.w += v0.w;
        a1.x += v1.x; a1.y += v1.y; a1.z += v1.z; a1.w += v1.w;
    }
    float4* av = (float4*)(out + OUT_AVG + (size_t)code * DIM);
    float4 c0 = av[lane], c1 = av[lane + 64];
    c0.x += 0.2f * a0.x; c0.y += 0.2f * a0.y; c0.z += 0.2f * a0.z; c0.w += 0.2f * a0.w;
    c1.x += 0.2f * a1.x; c1.y += 0.2f * a1.y; c1.z += 0.2f * a1.z; c1.w += 0.2f * a1.w;
    av[lane] = c0;
    av[lane + 64] = c1;
    if (lane == 0) out[OUT_CSN + code] += 0.2f * (float)n;
}

__global__ void sumInv_k(const float* __restrict__ out, float* __restrict__ Sout,
                         float* __restrict__ inv_cs) {
    __shared__ float red[4];
    float s = 0.f;
    for (int i = threadIdx.x; i < KCODES; i += 256) s += out[OUT_CSN + i];
    #pragma unroll
    for (int off = 32; off; off >>= 1) s += __shfl_down(s, off);
    if ((threadIdx.x & 63) == 0) red[threadIdx.x >> 6] = s;
    __syncthreads();
    float Sv = red[0] + red[1] + red[2] + red[3];
    if (threadIdx.x == 0) Sout[0] = Sv;
    for (int k = threadIdx.x; k < KCODES; k += 256)
        inv_cs[k] = (Sv + (float)KCODES * EPSF) / ((out[OUT_CSN + k] + EPSF) * Sv);
}

__global__ void normout_k(float* __restrict__ out, const float* __restrict__ inv_cs) {
    int i = blockIdx.x * 256 + threadIdx.x;
    const float4* avg = (const float4*)(out + OUT_AVG);
    float4* nrm = (float4*)(out + OUT_NORM);
    float inv = inv_cs[i >> 7];
    float4 v = avg[i];
    v.x *= inv; v.y *= inv; v.z *= inv; v.w *= inv;
    nrm[i] = v;
}

extern "C" void kernel_launch(void* const* d_in, const int* in_sizes, int n_in,
                              void* d_out, int out_size, void* d_ws, size_t ws_size,
                              hipStream_t stream) {
    const float* x     = (const float*)d_in[0];
    const float* embed = (const float*)d_in[1];
    const float* cs    = (const float*)d_in[2];
    const float* eavg  = (const float*)d_in[3];
    float* out = (float*)d_out;
    char*  w   = (char*)d_ws;

    unsigned long long* best = (unsigned long long*)w;
    float* norm2  = (float*)(w + 262144);
    float* Ssum   = (float*)(w + 294912);
    float* inv_cs = Ssum + 1;
    _Float16* Eh = (_Float16*)(w + (1u << 20));
    _Float16* Em = Eh + (size_t)KCODES * DIM;
    unsigned int* cnt     = (unsigned int*)(w + (20u << 20));
    unsigned int* rowlist = cnt + KCODES;

    _Float16* Xh = (_Float16*)out;
    _Float16* Xm = Xh + (size_t)N_ROWS * DIM;

    prep_k<<<10240, 256, 0, stream>>>(x, embed, Xh, Xm, Eh, Em, best, cnt, cs, eavg, out, norm2);
    dist_k<<<(N_ROWS / BM) * (KCODES / BN), 256, 0, stream>>>(Xh, Xm, Eh, Em, norm2, best);
    quant_slot_k<<<N_ROWS / 4, 256, 0, stream>>>(x, embed, best, cnt, rowlist, out);
    csum_k<<<KCODES, 64, 0, stream>>>(x, cnt, rowlist, out);
    sumInv_k<<<1, 256, 0, stream>>>(out, Ssum, inv_cs);
    normout_k<<<(KCODES * DIM / 4) / 256, 256, 0, stream>>>(out, inv_cs);
}